// Round 9
// baseline (200.418 us; speedup 1.0000x reference)
//
#include <hip/hip_runtime.h>

// IBNModel: graph-coupled bidirectional GRU + decoder. All fp32 in/out.
// B=16, H=64, N=512, C=3, E=128, D=32, L_OUT=12, LAYERS=2.
//
//  K1 prep : softmax(relu(E1 E2^T)) -> fp16 transposed AfT/AbT; adj -> adjT;
//            ufrag/wbfrag pre-scaled (-log2e for r,u / +2log2e for g); zpad.
//  K2 msg  : MFMA GEMM (x staged in XOR-swizzled LDS), cvt_pkrtz + b128
//            staging. Output rows PADDED to 32 B -> rec's per-step B-frag is
//            ONE aligned b128 (no mux/unpack VALU).
//  K3 rec  : R17 = R15 shape (8 waves, grid 512, 2 blocks/CU, BAR_LDS
//            lgkmcnt-only loop barriers, 15 pinned A-frags, u-gate in
//            phase 2, accr-lead in B2 shadow) + RCP PAIR-FOLDING:
//            rcp(a)*rcp(b)=rcp(a*b) cuts trans 20->16 per wave-step
//            (r-sigmoids 4rcp->2, blend 4rcp->2). Counter-derived: trans at
//            1/4 rate = 320 of ~390 VALU cyc/wave-step; VALUBusy==50% is
//            trans. [R16 lesson: forced phase anti-alignment is neutral --
//            phase mixing was never the limiter.]

typedef _Float16 half8_t __attribute__((ext_vector_type(8)));
typedef __fp16 fp16x2_t __attribute__((ext_vector_type(2)));
typedef float float4_t __attribute__((ext_vector_type(4)));

#define PIN(x) asm volatile("" : "+v"(x))

// LDS-only barrier: order ds ops across waves without draining vmcnt.
#define BAR_LDS()                                         \
  do {                                                    \
    asm volatile("s_waitcnt lgkmcnt(0)" ::: "memory");    \
    __builtin_amdgcn_s_barrier();                         \
  } while (0)

__device__ __forceinline__ float exp2_(float x) { return __builtin_amdgcn_exp2f(x); }
__device__ __forceinline__ float rcp_(float x) { return __builtin_amdgcn_rcpf(x); }

// ---------------- K1: prep --------------------------------------------------
__global__ __launch_bounds__(256) void prep_kernel(
    const float* __restrict__ E1f, const float* __restrict__ E2f,
    const float* __restrict__ E1b, const float* __restrict__ E2b,
    const float* __restrict__ adj, const float* __restrict__ Wf,
    const float* __restrict__ Uf, const float* __restrict__ bf,
    const float* __restrict__ Wb, const float* __restrict__ bb,
    _Float16* __restrict__ adjT, _Float16* __restrict__ AfT,
    _Float16* __restrict__ AbT, _Float16* __restrict__ ufrag,
    _Float16* __restrict__ wbfrag, _Float16* __restrict__ zpad) {
  int bid = blockIdx.x;
  int tid = threadIdx.x;
  if (bid >= 1288) {  // zero pad (16B-aligned zero source for q4>=2 lanes)
    if (tid < 64) zpad[tid] = (_Float16)0.f;
    return;
  }
  if (bid >= 1272) {  // wbfrag: 16 regions r2 = og*2 + (gi-1), pre-scaled
    int r2 = bid - 1272;
    int gi = 1 + (r2 & 1);
    int og = r2 >> 1;
    float scl = (gi == 2) ? 2.8853902f : -1.4426950f;
    for (int e = tid; e < 512; e += 256) {
      int lane = e >> 3, j = e & 7;
      int o = og * 16 + (lane & 15);
      int q = (lane >> 4) * 8 + j;
      float v = (q < 9) ? Wb[gi * 1152 + o * 9 + q]
                        : (q == 9 ? bb[gi * 128 + o] : 0.f);
      wbfrag[r2 * 512 + e] = (_Float16)(v * scl);
    }
    return;
  }
  if (bid >= 1152) {  // ufrag: 120 regions r = (og*3+gi)*5+kb, pre-scaled
    int r = bid - 1152;
    int kb = r % 5;
    int gi = (r / 5) % 3;
    int og = r / 15;
    float scl = (gi == 2) ? 2.8853902f : -1.4426950f;
    for (int e = tid; e < 512; e += 256) {
      int lane = e >> 3, j = e & 7;
      int o = og * 16 + (lane & 15);
      int q4 = lane >> 4;
      float v;
      if (kb < 4) {
        v = Uf[gi * 16384 + o * 128 + kb * 32 + q4 * 8 + j];
      } else {
        int q = q4 * 8 + j;
        v = (q < 9) ? Wf[gi * 1152 + o * 9 + q]
                    : (q == 9 ? bf[gi * 128 + o] : 0.f);
      }
      ufrag[r * 512 + e] = (_Float16)(v * scl);
    }
    return;
  }
  if (bid >= 1024) {  // adj -> adjT fp16 (transpose)
    int base = (bid - 1024) * 4;
    for (int r = 0; r < 4; ++r) {
      int row = base + r;
      float v0 = adj[row * 512 + tid];
      float v1 = adj[row * 512 + tid + 256];
      adjT[(size_t)tid * 512 + row] = (_Float16)v0;
      adjT[(size_t)(tid + 256) * 512 + row] = (_Float16)v1;
    }
    return;
  }
  int which = bid >> 9;
  int row = bid & 511;
  const float* E1 = which ? E1b : E1f;
  const float* E2 = which ? E2b : E2f;
  _Float16* A = which ? AbT : AfT;
  __shared__ float e1s[32];
  __shared__ float red[256];
  if (tid < 32) e1s[tid] = E1[row * 32 + tid];
  __syncthreads();
  float s[2];
#pragma unroll
  for (int h = 0; h < 2; ++h) {
    int m = tid + h * 256;
    const float4* e2 = (const float4*)(E2 + m * 32);
    float acc = 0.f;
#pragma unroll
    for (int d4 = 0; d4 < 8; ++d4) {
      float4 v = e2[d4];
      acc = fmaf(v.x, e1s[d4 * 4 + 0], acc);
      acc = fmaf(v.y, e1s[d4 * 4 + 1], acc);
      acc = fmaf(v.z, e1s[d4 * 4 + 2], acc);
      acc = fmaf(v.w, e1s[d4 * 4 + 3], acc);
    }
    s[h] = fmaxf(acc, 0.f);
  }
  red[tid] = fmaxf(s[0], s[1]);
  __syncthreads();
  for (int off = 128; off > 0; off >>= 1) {
    if (tid < off) red[tid] = fmaxf(red[tid], red[tid + off]);
    __syncthreads();
  }
  float mx = red[0];
  __syncthreads();
  float e0 = __expf(s[0] - mx), e1v = __expf(s[1] - mx);
  red[tid] = e0 + e1v;
  __syncthreads();
  for (int off = 128; off > 0; off >>= 1) {
    if (tid < off) red[tid] += red[tid + off];
    __syncthreads();
  }
  float inv = rcp_(red[0]);
  A[(size_t)tid * 512 + row] = (_Float16)(e0 * inv);
  A[(size_t)(tid + 256) * 512 + row] = (_Float16)(e1v * inv);
}

// ---------------- K2: message GEMM -> padded 32B rows -----------------------
// grid 512 = t(64) x nc(8, 64 cols); 256 thr = 4 waves (og = local n16 tile),
// 2 blocks/CU (80 KB LDS). Row layout (16 halves):
//   j0-2 = x, j3-5 = x@adj, j6-8 = x@Af (f2 at j8!), j9 = 1, j10-15 = 0.
__global__ __launch_bounds__(256, 2) void msg_kernel(
    const float* __restrict__ x, const _Float16* __restrict__ adjT,
    const _Float16* __restrict__ AfT, const _Float16* __restrict__ AbT,
    _Float16* __restrict__ msg16, _Float16* __restrict__ msgb16) {
  __shared__ __align__(16) _Float16 Alds[48 * 512];   // 48 KB
  __shared__ __align__(16) _Float16 Sst[1024 * 16];   // 32 KB
  int tid = threadIdx.x;
  int t = blockIdx.x >> 3;
  int n0g = (blockIdx.x & 7) * 64;
  int lane = tid & 63, og = tid >> 6;
  int l15 = lane & 15, q4 = lane >> 4, q0 = q4 * 8;
  bool is63 = (t == 63);

  // stage x -> Alds[m=b*3+c][k=n], XOR-swizzled. Per-task 24 contiguous
  // floats (6 aligned float4), de-interleave c via cvt_pkrtz, 3 ds_write_b128.
  {
    union F24 { float4 v4[6]; float f[24]; };
    union P16 { fp16x2_t h2[4]; uint4 u; };
#pragma unroll
    for (int it = 0; it < 4; ++it) {
      int task = tid + it * 256;          // 1024 tasks = b(16) x chunk(64)
      int b = task >> 6, chunk = task & 63;
      F24 fv;
      const float4* xb4 = (const float4*)x + ((size_t)(b * 64 + t) * 384 + chunk * 6);
#pragma unroll
      for (int i = 0; i < 6; ++i) fv.v4[i] = xb4[i];
#pragma unroll
      for (int c = 0; c < 3; ++c) {
        P16 p;
#pragma unroll
        for (int i = 0; i < 4; ++i)
          p.h2[i] = __builtin_amdgcn_cvt_pkrtz(fv.f[6 * i + c], fv.f[6 * i + 3 + c]);
        int m = b * 3 + c;
        *(uint4*)&Alds[m * 512 + ((chunk ^ (m & 7)) << 3)] = p.u;
      }
    }
  }
  __syncthreads();

  const float4_t zero4 = {0.f, 0.f, 0.f, 0.f};
  float4_t acc[3][2], accb[3];
#pragma unroll
  for (int mt = 0; mt < 3; ++mt) { acc[mt][0] = zero4; acc[mt][1] = zero4; accb[mt] = zero4; }

  int n = n0g + og * 16 + l15;
  for (int kb = 0; kb < 16; ++kb) {
    half8_t afr[3];
#pragma unroll
    for (int mt = 0; mt < 3; ++mt) {
      int m = mt * 16 + l15;
      afr[mt] = *(const half8_t*)&Alds[m * 512 + ((((kb * 4 + q4) ^ (m & 7)) << 3))];
    }
    half8_t b0 = *(const half8_t*)&adjT[(size_t)n * 512 + kb * 32 + q0];
    half8_t b1 = *(const half8_t*)&AfT[(size_t)n * 512 + kb * 32 + q0];
#pragma unroll
    for (int mt = 0; mt < 3; ++mt) {
      acc[mt][0] = __builtin_amdgcn_mfma_f32_16x16x32_f16(afr[mt], b0, acc[mt][0], 0, 0, 0);
      acc[mt][1] = __builtin_amdgcn_mfma_f32_16x16x32_f16(afr[mt], b1, acc[mt][1], 0, 0, 0);
    }
    if (is63) {
      half8_t b2 = *(const half8_t*)&AbT[(size_t)n * 512 + kb * 32 + q0];
#pragma unroll
      for (int mt = 0; mt < 3; ++mt)
        accb[mt] = __builtin_amdgcn_mfma_f32_16x16x32_f16(afr[mt], b2, accb[mt], 0, 0, 0);
    }
  }

  // fill x (j0-2), bias (j9), zeros (j10-15)
  for (int i = tid; i < 1024; i += 256) {
    int tb = i >> 6, nl = i & 63;
    int nn = n0g + nl;
    _Float16* row = &Sst[i * 16];
#pragma unroll
    for (int c = 0; c < 3; ++c) {
      int m = tb * 3 + c;
      row[c] = Alds[m * 512 + ((((nn >> 3) ^ (m & 7)) << 3) | (nn & 7))];
    }
    row[9] = (_Float16)1.f;
#pragma unroll
    for (int z = 10; z < 16; ++z) row[z] = (_Float16)0.f;
  }
  // MFMA results (C layout: col=l15, row=q4*4+r)
#pragma unroll
  for (int mt = 0; mt < 3; ++mt)
#pragma unroll
    for (int r = 0; r < 4; ++r) {
      int m = mt * 16 + q4 * 4 + r;
      int tb = (m * 21846) >> 16;
      int c = m - tb * 3;
      _Float16* row = &Sst[(tb * 64 + og * 16 + l15) * 16];
      row[3 + c] = (_Float16)acc[mt][0][r];
      row[6 + c] = (_Float16)acc[mt][1][r];
    }
  __syncthreads();
  // coalesced copy-out: 2 uint4 per row
  for (int i = tid; i < 2048; i += 256) {
    int rrow = i >> 1, h = i & 1;
    int tb = rrow >> 6, nl = rrow & 63;
    ((uint4*)msg16)[(((size_t)(t * 16 + tb) * 512) + n0g + nl) * 2 + h] =
        ((const uint4*)Sst)[i];
  }
  if (is63) {
    __syncthreads();  // copy-out done before overwrite
#pragma unroll
    for (int mt = 0; mt < 3; ++mt)
#pragma unroll
      for (int r = 0; r < 4; ++r) {
        int m = mt * 16 + q4 * 4 + r;
        int tb = (m * 21846) >> 16;
        int c = m - tb * 3;
        Sst[(tb * 64 + og * 16 + l15) * 16 + 6 + c] = (_Float16)accb[mt][r];
      }
    __syncthreads();
    for (int i = tid; i < 2048; i += 256) {
      int rrow = i >> 1, h = i & 1;
      int tb = rrow >> 6, nl = rrow & 63;
      ((uint4*)msgb16)[(((size_t)tb * 512) + n0g + nl) * 2 + h] =
          ((const uint4*)Sst)[i];
    }
  }
}

// ---------------- K3: MFMA recurrence + backward + decoder ------------------
// R17: R15 structure -- grid 512 = b(16) x ntile(32, 16 cols); 512 thr =
// 8 waves, 2 blocks/CU. Phase 1 = r-chain only; u-gate in phase 2; accr-lead
// in B2 shadow; BAR_LDS loop barriers. NEW: rcp pair-folding in both
// activation blocks (trans 20 -> 16 per wave-step).
__global__ __launch_bounds__(512, 4) void rec_kernel(
    const _Float16* __restrict__ msg16, const _Float16* __restrict__ msgb16,
    const _Float16* __restrict__ zpad, const _Float16* __restrict__ ufrag,
    const _Float16* __restrict__ wbfrag, const float* __restrict__ dec_w,
    const float* __restrict__ dec_b, const float* __restrict__ out_w,
    const float* __restrict__ out_b, float* __restrict__ out) {
  __shared__ __align__(16) _Float16 Cbuf[2048];  // 4 KB
  __shared__ __align__(16) _Float16 Gbuf[2048];  // 4 KB
  __shared__ float hf_lds[128 * 16];
  __shared__ float hb_lds[128 * 16];
  __shared__ float hdec_lds[12 * 16];
  int tid = threadIdx.x, bid = blockIdx.x;
  int b = bid >> 5;
  int nt = bid & 31;
  int n0 = nt * 16;
  int lane = tid & 63, og = tid >> 6;
  int l15 = lane & 15, q4 = lane >> 4;

  half8_t afrag[3][5];
#pragma unroll
  for (int gi = 0; gi < 3; ++gi)
#pragma unroll
    for (int kb = 0; kb < 5; ++kb) {
      afrag[gi][kb] = *(const half8_t*)
          &ufrag[(size_t)(((og * 3 + gi) * 5 + kb) * 512) + lane * 8];
      PIN(afrag[gi][kb]);
    }

  if (tid < 256) {
    uint4 z; z.x = z.y = z.z = z.w = 0;
    ((uint4*)Cbuf)[tid] = z;
  }
  float cr[4] = {0.f, 0.f, 0.f, 0.f};

  const float4_t zero4 = {0.f, 0.f, 0.f, 0.f};
  union H4U { fp16x2_t h2[2]; unsigned long long u; };
  // padded-row message stream: one aligned b128 per step, no mux.
  // lanes q4>=2 (k=16-31, all-zero rows) read the 16B zero pad.
  const char* base = (const char*)msg16 +
                     ((size_t)(b * 512 + n0 + l15)) * 32 + (q4 & 1) * 16;
  const char* pcur = (q4 < 2) ? base : (const char*)zpad;
  size_t tstr = (q4 < 2) ? (size_t)16 * 512 * 32 : 0;
  half8_t bm = *(const half8_t*)pcur;  // t=0

  // t=0 r-gate lead (register-only; legal before the barrier)
  float4_t accr_p = __builtin_amdgcn_mfma_f32_16x16x32_f16(afrag[0][4], bm, zero4, 0, 0, 0);

  int kb_w = og >> 1;
  int lane_w = ((og & 1) * 2 + (q4 >> 1)) * 16 + l15;
  int j0 = (q4 & 1) * 4;
  __syncthreads();

  for (int t = 0; t < 64; ++t) {
    // prefetch next step's frag (pointer increment; t=64 over-read stays
    // inside msgb16 -- max end byte == workspace end, unused)
    const char* pnext = pcur + tstr;
    half8_t bm_n = *(const half8_t*)pnext;

    half8_t cf[4];
#pragma unroll
    for (int kb = 0; kb < 4; ++kb)
      cf[kb] = *(const half8_t*)&Cbuf[(kb * 64 + lane) * 8];

    // ---- phase 1: r-chain only ----
    float4_t accr = accr_p;
    __builtin_amdgcn_s_setprio(1);
#pragma unroll
    for (int kb = 0; kb < 4; ++kb)
      accr = __builtin_amdgcn_mfma_f32_16x16x32_f16(afrag[0][kb], cf[kb], accr, 0, 0, 0);
    __builtin_amdgcn_s_setprio(0);

    {  // pair-folded sigmoid*c: R = rcp((1+Ea)(1+Eb));
      // ra = c_a*(1+Eb)*R, rb = c_b*(1+Ea)*R   [2 rcp instead of 4]
      H4U v;
#pragma unroll
      for (int r = 0; r < 2; ++r) {
        float Ea = exp2_(accr[2 * r]);
        float Eb = exp2_(accr[2 * r + 1]);
        float da = 1.f + Ea, db = 1.f + Eb;
        float R = rcp_(da * db);
        float a = cr[2 * r] * db * R;
        float bq = cr[2 * r + 1] * da * R;
        v.h2[r] = __builtin_amdgcn_cvt_pkrtz(a, bq);
      }
      *(unsigned long long*)&Gbuf[(kb_w * 64 + lane_w) * 8 + j0] = v.u;
    }
    BAR_LDS();  // B1: rc visible; Cbuf reads done (vmcnt NOT drained)

    // ---- phase 2: u-chain (overlaps gf read) + g-chain + blend ----
    half8_t gf[4];
#pragma unroll
    for (int kb = 0; kb < 4; ++kb)
      gf[kb] = *(const half8_t*)&Gbuf[(kb * 64 + lane) * 8];
    __builtin_amdgcn_s_setprio(1);
    float4_t accu = __builtin_amdgcn_mfma_f32_16x16x32_f16(afrag[1][4], bm, zero4, 0, 0, 0);
#pragma unroll
    for (int kb = 0; kb < 4; ++kb)
      accu = __builtin_amdgcn_mfma_f32_16x16x32_f16(afrag[1][kb], cf[kb], accu, 0, 0, 0);
    float4_t accg = __builtin_amdgcn_mfma_f32_16x16x32_f16(afrag[2][4], bm, zero4, 0, 0, 0);
#pragma unroll
    for (int kb = 0; kb < 4; ++kb)
      accg = __builtin_amdgcn_mfma_f32_16x16x32_f16(afrag[2][kb], gf[kb], accg, 0, 0, 0);
    __builtin_amdgcn_s_setprio(0);

    {  // fused blend with pair-folded rcp: Eu=e^{-pre_u}, Eg=e^{2*pre_g},
      // c' = [c*(Eg+1) + Eu*(Eg-1)] / [(1+Eu)*(1+Eg)];
      // R = rcp(den0*den1); cn0 = num0*den1*R, cn1 = num1*den0*R.
      // Overflow audit: den0*den1 <= ~2^48 for this data (|pre|<~10).
      H4U v;
      float cn[4];
#pragma unroll
      for (int r = 0; r < 4; r += 2) {
        float Eu0 = exp2_(accu[r]), Eg0 = exp2_(accg[r]);
        float Eu1 = exp2_(accu[r + 1]), Eg1 = exp2_(accg[r + 1]);
        float d00 = Eg0 + 1.f, d01 = Eg1 + 1.f;
        float den0 = fmaf(Eu0, d00, d00);
        float den1 = fmaf(Eu1, d01, d01);
        float num0 = fmaf(cr[r], Eg0, cr[r]) + fmaf(Eu0, Eg0, -Eu0);
        float num1 = fmaf(cr[r + 1], Eg1, cr[r + 1]) + fmaf(Eu1, Eg1, -Eu1);
        float R = rcp_(den0 * den1);
        cn[r] = num0 * den1 * R;
        cn[r + 1] = num1 * den0 * R;
        cr[r] = cn[r];
        cr[r + 1] = cn[r + 1];
      }
      v.h2[0] = __builtin_amdgcn_cvt_pkrtz(cn[0], cn[1]);
      v.h2[1] = __builtin_amdgcn_cvt_pkrtz(cn[2], cn[3]);
      *(unsigned long long*)&Cbuf[(kb_w * 64 + lane_w) * 8 + j0] = v.u;
    }
    // barrier-2 shadow: r-gate lead for step t+1 (register-only)
    accr_p = __builtin_amdgcn_mfma_f32_16x16x32_f16(afrag[0][4], bm_n, zero4, 0, 0, 0);
    BAR_LDS();  // B2: c_{t+1} visible; Gbuf reads done
    bm = bm_n;
    pcur = pnext;
  }

  // backward cell at t=63, c0=0: h_back = (1-sig(pre_u))*tanh(pre_g)
  {
    const char* bb_base = (const char*)msgb16 +
                          ((size_t)(b * 512 + n0 + l15)) * 32 + (q4 & 1) * 16;
    const char* bp = (q4 < 2) ? bb_base : (const char*)zpad;
    half8_t bbk = *(const half8_t*)bp;
    half8_t au_f = *(const half8_t*)&wbfrag[(size_t)((og * 2 + 0) * 512) + lane * 8];
    half8_t ag_f = *(const half8_t*)&wbfrag[(size_t)((og * 2 + 1) * 512) + lane * 8];
    float4_t au = __builtin_amdgcn_mfma_f32_16x16x32_f16(au_f, bbk, zero4, 0, 0, 0);
    float4_t ag = __builtin_amdgcn_mfma_f32_16x16x32_f16(ag_f, bbk, zero4, 0, 0, 0);
#pragma unroll
    for (int r = 0; r < 4; ++r) {
      int row = og * 16 + q4 * 4 + r;
      float uu2 = rcp_(1.f + exp2_(au[r]));
      float gg = fmaf(-2.f, rcp_(exp2_(ag[r]) + 1.f), 1.f);
      hb_lds[row * 16 + l15] = (1.f - uu2) * gg;
      hf_lds[row * 16 + l15] = cr[r];
    }
  }
  __syncthreads();

  // decoder
  if (tid < 192) {
    int i = tid >> 4, cc = tid & 15;
    const float* dwa = dec_w + (size_t)i * 512;
    const float* dwb = dwa + 256;
    float hd = dec_b[i];
    for (int e = 0; e < 128; ++e) {
      hd = fmaf(dwa[e] + dwb[e], hf_lds[e * 16 + cc], hd);
      hd = fmaf(dwa[128 + e] + dwb[128 + e], hb_lds[e * 16 + cc], hd);
    }
    hdec_lds[i * 16 + cc] = hd;
  }
  __syncthreads();
  if (tid < 192) {
    int o = tid >> 4, cc = tid & 15;
    float v = out_b[o];
#pragma unroll
    for (int i = 0; i < 12; ++i) v = fmaf(out_w[o * 12 + i], hdec_lds[i * 16 + cc], v);
    out[((size_t)(b * 12 + o)) * 512 + n0 + cc] = v;
  }
}

extern "C" void kernel_launch(void* const* d_in, const int* in_sizes, int n_in,
                              void* d_out, int out_size, void* d_ws, size_t ws_size,
                              hipStream_t stream) {
  (void)in_sizes; (void)n_in; (void)out_size; (void)ws_size;
  const float* x     = (const float*)d_in[0];
  const float* adj   = (const float*)d_in[1];
  const float* Wf    = (const float*)d_in[2];
  const float* Uf    = (const float*)d_in[3];
  const float* bf    = (const float*)d_in[4];
  const float* E1f   = (const float*)d_in[5];
  const float* E2f   = (const float*)d_in[6];
  const float* Wb    = (const float*)d_in[7];
  const float* bb    = (const float*)d_in[9];
  const float* E1b   = (const float*)d_in[10];
  const float* E2b   = (const float*)d_in[11];
  const float* dec_w = (const float*)d_in[12];
  const float* dec_b = (const float*)d_in[13];
  const float* out_w = (const float*)d_in[14];
  const float* out_b = (const float*)d_in[15];

  _Float16* h      = (_Float16*)d_ws;
  _Float16* adjT   = h;                        //   262144
  _Float16* AfT    = h + 262144;               //   262144
  _Float16* AbT    = h + 524288;               //   262144
  _Float16* ufrag  = h + 786432;               //    61440
  _Float16* wbfrag = h + 847872;               //     8192
  _Float16* zpad   = h + 856064;               //       64
  _Float16* msg16  = h + 856128;               //  8388608 (32B rows)
  _Float16* msgb16 = h + 9244736;              //   131072 (also t=64 over-read pad)
  // total 9,375,808 halves ≈ 18.75 MB

  prep_kernel<<<1289, 256, 0, stream>>>(E1f, E2f, E1b, E2b, adj, Wf, Uf, bf,
                                        Wb, bb, adjT, AfT, AbT, ufrag, wbfrag, zpad);
  msg_kernel<<<512, 256, 0, stream>>>(x, adjT, AfT, AbT, msg16, msgb16);
  rec_kernel<<<512, 512, 0, stream>>>(msg16, msgb16, zpad, ufrag, wbfrag,
                                      dec_w, dec_b, out_w, out_b, (float*)d_out);
}

// Round 10
// 195.447 us; speedup vs baseline: 1.0254x; 1.0254x over previous
//
#include <hip/hip_runtime.h>

// IBNModel: graph-coupled bidirectional GRU + decoder. All fp32 in/out.
// B=16, H=64, N=512, C=3, E=128, D=32, L_OUT=12, LAYERS=2.
//
//  K1 prep : softmax(relu(E1 E2^T)) -> fp16 transposed AfT/AbT; adj -> adjT;
//            ufrag/wbfrag pre-scaled (-log2e for r,u / +2log2e for g); zpad.
//  K2 msg  : MFMA GEMM (x staged in XOR-swizzled LDS), cvt_pkrtz + b128
//            staging (12 LDS instr/thread). Output rows PADDED to 32 B:
//            [x0,x1,x2,a0,a1,a2,f0,f1 | f2,1,0,0,0,0,0,0] -> rec's per-step
//            B-frag is ONE aligned b128 (no mux/unpack VALU).
//  K3 rec  : R18 = R12 EXACT (verified best: 195.8 us total, rec 82.2):
//            8 waves, grid 512, 2 blocks/CU, 2 barriers/step, 15 pinned
//            A-frags. Phase 1 = r-chain ONLY (B1 waits just on rc); u-gate
//            in phase 2 overlapping gf's ds_read; accr-lead in B2 shadow.
//            Single-rcp fused u/g blend, exp2 activations, pkrtz packing,
//            pointer-increment prefetch (t=64 over-read bounds-verified).
//            Session ledger: refuted levers -- MFMA tree split (R14 -12%:
//            breaks same-accumulator pipe chaining), rcp pair-folding (R17
//            -4%: lengthens serial activation chain; latency-bound not
//            throughput-bound), forced phase anti-alignment (R16 neutral),
//            lgkmcnt-only barriers (R15 neutral), 1 block/CU or <8 waves
//            (R10/R11 -12..20%). Plateau: 128 serial barrier-phases x
//            ~1540cy (bursty all-to-all LDS broadcast + 16-wave barrier
//            convergence); no pipe saturated (MFMA 33/VALU 50/LDS 56/HBM 1).

typedef _Float16 half8_t __attribute__((ext_vector_type(8)));
typedef __fp16 fp16x2_t __attribute__((ext_vector_type(2)));
typedef float float4_t __attribute__((ext_vector_type(4)));

#define PIN(x) asm volatile("" : "+v"(x))

__device__ __forceinline__ float exp2_(float x) { return __builtin_amdgcn_exp2f(x); }
__device__ __forceinline__ float rcp_(float x) { return __builtin_amdgcn_rcpf(x); }

// ---------------- K1: prep --------------------------------------------------
__global__ __launch_bounds__(256) void prep_kernel(
    const float* __restrict__ E1f, const float* __restrict__ E2f,
    const float* __restrict__ E1b, const float* __restrict__ E2b,
    const float* __restrict__ adj, const float* __restrict__ Wf,
    const float* __restrict__ Uf, const float* __restrict__ bf,
    const float* __restrict__ Wb, const float* __restrict__ bb,
    _Float16* __restrict__ adjT, _Float16* __restrict__ AfT,
    _Float16* __restrict__ AbT, _Float16* __restrict__ ufrag,
    _Float16* __restrict__ wbfrag, _Float16* __restrict__ zpad) {
  int bid = blockIdx.x;
  int tid = threadIdx.x;
  if (bid >= 1288) {  // zero pad (16B-aligned zero source for q4>=2 lanes)
    if (tid < 64) zpad[tid] = (_Float16)0.f;
    return;
  }
  if (bid >= 1272) {  // wbfrag: 16 regions r2 = og*2 + (gi-1), pre-scaled
    int r2 = bid - 1272;
    int gi = 1 + (r2 & 1);
    int og = r2 >> 1;
    float scl = (gi == 2) ? 2.8853902f : -1.4426950f;
    for (int e = tid; e < 512; e += 256) {
      int lane = e >> 3, j = e & 7;
      int o = og * 16 + (lane & 15);
      int q = (lane >> 4) * 8 + j;
      float v = (q < 9) ? Wb[gi * 1152 + o * 9 + q]
                        : (q == 9 ? bb[gi * 128 + o] : 0.f);
      wbfrag[r2 * 512 + e] = (_Float16)(v * scl);
    }
    return;
  }
  if (bid >= 1152) {  // ufrag: 120 regions r = (og*3+gi)*5+kb, pre-scaled
    int r = bid - 1152;
    int kb = r % 5;
    int gi = (r / 5) % 3;
    int og = r / 15;
    float scl = (gi == 2) ? 2.8853902f : -1.4426950f;
    for (int e = tid; e < 512; e += 256) {
      int lane = e >> 3, j = e & 7;
      int o = og * 16 + (lane & 15);
      int q4 = lane >> 4;
      float v;
      if (kb < 4) {
        v = Uf[gi * 16384 + o * 128 + kb * 32 + q4 * 8 + j];
      } else {
        int q = q4 * 8 + j;
        v = (q < 9) ? Wf[gi * 1152 + o * 9 + q]
                    : (q == 9 ? bf[gi * 128 + o] : 0.f);
      }
      ufrag[r * 512 + e] = (_Float16)(v * scl);
    }
    return;
  }
  if (bid >= 1024) {  // adj -> adjT fp16 (transpose)
    int base = (bid - 1024) * 4;
    for (int r = 0; r < 4; ++r) {
      int row = base + r;
      float v0 = adj[row * 512 + tid];
      float v1 = adj[row * 512 + tid + 256];
      adjT[(size_t)tid * 512 + row] = (_Float16)v0;
      adjT[(size_t)(tid + 256) * 512 + row] = (_Float16)v1;
    }
    return;
  }
  int which = bid >> 9;
  int row = bid & 511;
  const float* E1 = which ? E1b : E1f;
  const float* E2 = which ? E2b : E2f;
  _Float16* A = which ? AbT : AfT;
  __shared__ float e1s[32];
  __shared__ float red[256];
  if (tid < 32) e1s[tid] = E1[row * 32 + tid];
  __syncthreads();
  float s[2];
#pragma unroll
  for (int h = 0; h < 2; ++h) {
    int m = tid + h * 256;
    const float4* e2 = (const float4*)(E2 + m * 32);
    float acc = 0.f;
#pragma unroll
    for (int d4 = 0; d4 < 8; ++d4) {
      float4 v = e2[d4];
      acc = fmaf(v.x, e1s[d4 * 4 + 0], acc);
      acc = fmaf(v.y, e1s[d4 * 4 + 1], acc);
      acc = fmaf(v.z, e1s[d4 * 4 + 2], acc);
      acc = fmaf(v.w, e1s[d4 * 4 + 3], acc);
    }
    s[h] = fmaxf(acc, 0.f);
  }
  red[tid] = fmaxf(s[0], s[1]);
  __syncthreads();
  for (int off = 128; off > 0; off >>= 1) {
    if (tid < off) red[tid] = fmaxf(red[tid], red[tid + off]);
    __syncthreads();
  }
  float mx = red[0];
  __syncthreads();
  float e0 = __expf(s[0] - mx), e1v = __expf(s[1] - mx);
  red[tid] = e0 + e1v;
  __syncthreads();
  for (int off = 128; off > 0; off >>= 1) {
    if (tid < off) red[tid] += red[tid + off];
    __syncthreads();
  }
  float inv = rcp_(red[0]);
  A[(size_t)tid * 512 + row] = (_Float16)(e0 * inv);
  A[(size_t)(tid + 256) * 512 + row] = (_Float16)(e1v * inv);
}

// ---------------- K2: message GEMM -> padded 32B rows -----------------------
// grid 512 = t(64) x nc(8, 64 cols); 256 thr = 4 waves (og = local n16 tile),
// 2 blocks/CU (80 KB LDS). Row layout (16 halves):
//   j0-2 = x, j3-5 = x@adj, j6-8 = x@Af (f2 at j8!), j9 = 1, j10-15 = 0.
__global__ __launch_bounds__(256, 2) void msg_kernel(
    const float* __restrict__ x, const _Float16* __restrict__ adjT,
    const _Float16* __restrict__ AfT, const _Float16* __restrict__ AbT,
    _Float16* __restrict__ msg16, _Float16* __restrict__ msgb16) {
  __shared__ __align__(16) _Float16 Alds[48 * 512];   // 48 KB
  __shared__ __align__(16) _Float16 Sst[1024 * 16];   // 32 KB
  int tid = threadIdx.x;
  int t = blockIdx.x >> 3;
  int n0g = (blockIdx.x & 7) * 64;
  int lane = tid & 63, og = tid >> 6;
  int l15 = lane & 15, q4 = lane >> 4, q0 = q4 * 8;
  bool is63 = (t == 63);

  // stage x -> Alds[m=b*3+c][k=n], XOR-swizzled. Per-task 24 contiguous
  // floats (6 aligned float4), de-interleave c via cvt_pkrtz, 3 ds_write_b128.
  {
    union F24 { float4 v4[6]; float f[24]; };
    union P16 { fp16x2_t h2[4]; uint4 u; };
#pragma unroll
    for (int it = 0; it < 4; ++it) {
      int task = tid + it * 256;          // 1024 tasks = b(16) x chunk(64)
      int b = task >> 6, chunk = task & 63;
      F24 fv;
      const float4* xb4 = (const float4*)x + ((size_t)(b * 64 + t) * 384 + chunk * 6);
#pragma unroll
      for (int i = 0; i < 6; ++i) fv.v4[i] = xb4[i];
#pragma unroll
      for (int c = 0; c < 3; ++c) {
        P16 p;
#pragma unroll
        for (int i = 0; i < 4; ++i)
          p.h2[i] = __builtin_amdgcn_cvt_pkrtz(fv.f[6 * i + c], fv.f[6 * i + 3 + c]);
        int m = b * 3 + c;
        *(uint4*)&Alds[m * 512 + ((chunk ^ (m & 7)) << 3)] = p.u;
      }
    }
  }
  __syncthreads();

  const float4_t zero4 = {0.f, 0.f, 0.f, 0.f};
  float4_t acc[3][2], accb[3];
#pragma unroll
  for (int mt = 0; mt < 3; ++mt) { acc[mt][0] = zero4; acc[mt][1] = zero4; accb[mt] = zero4; }

  int n = n0g + og * 16 + l15;
  for (int kb = 0; kb < 16; ++kb) {
    half8_t afr[3];
#pragma unroll
    for (int mt = 0; mt < 3; ++mt) {
      int m = mt * 16 + l15;
      afr[mt] = *(const half8_t*)&Alds[m * 512 + ((((kb * 4 + q4) ^ (m & 7)) << 3))];
    }
    half8_t b0 = *(const half8_t*)&adjT[(size_t)n * 512 + kb * 32 + q0];
    half8_t b1 = *(const half8_t*)&AfT[(size_t)n * 512 + kb * 32 + q0];
#pragma unroll
    for (int mt = 0; mt < 3; ++mt) {
      acc[mt][0] = __builtin_amdgcn_mfma_f32_16x16x32_f16(afr[mt], b0, acc[mt][0], 0, 0, 0);
      acc[mt][1] = __builtin_amdgcn_mfma_f32_16x16x32_f16(afr[mt], b1, acc[mt][1], 0, 0, 0);
    }
    if (is63) {
      half8_t b2 = *(const half8_t*)&AbT[(size_t)n * 512 + kb * 32 + q0];
#pragma unroll
      for (int mt = 0; mt < 3; ++mt)
        accb[mt] = __builtin_amdgcn_mfma_f32_16x16x32_f16(afr[mt], b2, accb[mt], 0, 0, 0);
    }
  }

  // fill x (j0-2), bias (j9), zeros (j10-15)
  for (int i = tid; i < 1024; i += 256) {
    int tb = i >> 6, nl = i & 63;
    int nn = n0g + nl;
    _Float16* row = &Sst[i * 16];
#pragma unroll
    for (int c = 0; c < 3; ++c) {
      int m = tb * 3 + c;
      row[c] = Alds[m * 512 + ((((nn >> 3) ^ (m & 7)) << 3) | (nn & 7))];
    }
    row[9] = (_Float16)1.f;
#pragma unroll
    for (int z = 10; z < 16; ++z) row[z] = (_Float16)0.f;
  }
  // MFMA results (C layout: col=l15, row=q4*4+r)
#pragma unroll
  for (int mt = 0; mt < 3; ++mt)
#pragma unroll
    for (int r = 0; r < 4; ++r) {
      int m = mt * 16 + q4 * 4 + r;
      int tb = (m * 21846) >> 16;
      int c = m - tb * 3;
      _Float16* row = &Sst[(tb * 64 + og * 16 + l15) * 16];
      row[3 + c] = (_Float16)acc[mt][0][r];
      row[6 + c] = (_Float16)acc[mt][1][r];
    }
  __syncthreads();
  // coalesced copy-out: 2 uint4 per row
  for (int i = tid; i < 2048; i += 256) {
    int rrow = i >> 1, h = i & 1;
    int tb = rrow >> 6, nl = rrow & 63;
    ((uint4*)msg16)[(((size_t)(t * 16 + tb) * 512) + n0g + nl) * 2 + h] =
        ((const uint4*)Sst)[i];
  }
  if (is63) {
    __syncthreads();  // copy-out done before overwrite
#pragma unroll
    for (int mt = 0; mt < 3; ++mt)
#pragma unroll
      for (int r = 0; r < 4; ++r) {
        int m = mt * 16 + q4 * 4 + r;
        int tb = (m * 21846) >> 16;
        int c = m - tb * 3;
        Sst[(tb * 64 + og * 16 + l15) * 16 + 6 + c] = (_Float16)accb[mt][r];
      }
    __syncthreads();
    for (int i = tid; i < 2048; i += 256) {
      int rrow = i >> 1, h = i & 1;
      int tb = rrow >> 6, nl = rrow & 63;
      ((uint4*)msgb16)[(((size_t)tb * 512) + n0g + nl) * 2 + h] =
          ((const uint4*)Sst)[i];
    }
  }
}

// ---------------- K3: MFMA recurrence + backward + decoder ------------------
// R18 = R12: grid 512 = b(16) x ntile(32, 16 cols); 512 thr = 8 waves,
// 2 blocks/CU (4 waves/SIMD). Wave og owns rows og*16..+15; 15 pinned
// A-frags. Phase 1 = r-chain ONLY (B1 waits just on rc); u-gate runs in
// phase 2 overlapping gf's ds_read; accr-lead hoisted into B2's shadow.
__global__ __launch_bounds__(512, 4) void rec_kernel(
    const _Float16* __restrict__ msg16, const _Float16* __restrict__ msgb16,
    const _Float16* __restrict__ zpad, const _Float16* __restrict__ ufrag,
    const _Float16* __restrict__ wbfrag, const float* __restrict__ dec_w,
    const float* __restrict__ dec_b, const float* __restrict__ out_w,
    const float* __restrict__ out_b, float* __restrict__ out) {
  __shared__ __align__(16) _Float16 Cbuf[2048];  // 4 KB
  __shared__ __align__(16) _Float16 Gbuf[2048];  // 4 KB
  __shared__ float hf_lds[128 * 16];
  __shared__ float hb_lds[128 * 16];
  __shared__ float hdec_lds[12 * 16];
  int tid = threadIdx.x, bid = blockIdx.x;
  int b = bid >> 5;
  int nt = bid & 31;
  int n0 = nt * 16;
  int lane = tid & 63, og = tid >> 6;
  int l15 = lane & 15, q4 = lane >> 4;

  half8_t afrag[3][5];
#pragma unroll
  for (int gi = 0; gi < 3; ++gi)
#pragma unroll
    for (int kb = 0; kb < 5; ++kb) {
      afrag[gi][kb] = *(const half8_t*)
          &ufrag[(size_t)(((og * 3 + gi) * 5 + kb) * 512) + lane * 8];
      PIN(afrag[gi][kb]);
    }

  if (tid < 256) {
    uint4 z; z.x = z.y = z.z = z.w = 0;
    ((uint4*)Cbuf)[tid] = z;
  }
  float cr[4] = {0.f, 0.f, 0.f, 0.f};

  const float4_t zero4 = {0.f, 0.f, 0.f, 0.f};
  union H4U { fp16x2_t h2[2]; unsigned long long u; };
  // padded-row message stream: one aligned b128 per step, no mux.
  // lanes q4>=2 (k=16-31, all-zero rows) read the 16B zero pad.
  const char* base = (const char*)msg16 +
                     ((size_t)(b * 512 + n0 + l15)) * 32 + (q4 & 1) * 16;
  const char* pcur = (q4 < 2) ? base : (const char*)zpad;
  size_t tstr = (q4 < 2) ? (size_t)16 * 512 * 32 : 0;
  half8_t bm = *(const half8_t*)pcur;  // t=0

  // t=0 r-gate lead (register-only; legal before the barrier)
  float4_t accr_p = __builtin_amdgcn_mfma_f32_16x16x32_f16(afrag[0][4], bm, zero4, 0, 0, 0);

  int kb_w = og >> 1;
  int lane_w = ((og & 1) * 2 + (q4 >> 1)) * 16 + l15;
  int j0 = (q4 & 1) * 4;
  __syncthreads();

  for (int t = 0; t < 64; ++t) {
    // prefetch next step's frag (pointer increment; t=63 over-read stays
    // inside msgb16 -- max end byte == workspace end, unused)
    const char* pnext = pcur + tstr;
    half8_t bm_n = *(const half8_t*)pnext;

    half8_t cf[4];
#pragma unroll
    for (int kb = 0; kb < 4; ++kb)
      cf[kb] = *(const half8_t*)&Cbuf[(kb * 64 + lane) * 8];

    // ---- phase 1: r-chain only ----
    float4_t accr = accr_p;
    __builtin_amdgcn_s_setprio(1);
#pragma unroll
    for (int kb = 0; kb < 4; ++kb)
      accr = __builtin_amdgcn_mfma_f32_16x16x32_f16(afrag[0][kb], cf[kb], accr, 0, 0, 0);
    __builtin_amdgcn_s_setprio(0);

    {  // r = rcp(1+exp2(.)) [pre-scaled -log2e]; rc -> Gbuf
      H4U v;
#pragma unroll
      for (int r = 0; r < 2; ++r) {
        float a = rcp_(1.f + exp2_(accr[2 * r])) * cr[2 * r];
        float bq = rcp_(1.f + exp2_(accr[2 * r + 1])) * cr[2 * r + 1];
        v.h2[r] = __builtin_amdgcn_cvt_pkrtz(a, bq);
      }
      *(unsigned long long*)&Gbuf[(kb_w * 64 + lane_w) * 8 + j0] = v.u;
    }
    __syncthreads();  // B1: rc visible; Cbuf reads done

    // ---- phase 2: u-chain (overlaps gf read) + g-chain + blend ----
    half8_t gf[4];
#pragma unroll
    for (int kb = 0; kb < 4; ++kb)
      gf[kb] = *(const half8_t*)&Gbuf[(kb * 64 + lane) * 8];
    __builtin_amdgcn_s_setprio(1);
    float4_t accu = __builtin_amdgcn_mfma_f32_16x16x32_f16(afrag[1][4], bm, zero4, 0, 0, 0);
#pragma unroll
    for (int kb = 0; kb < 4; ++kb)
      accu = __builtin_amdgcn_mfma_f32_16x16x32_f16(afrag[1][kb], cf[kb], accu, 0, 0, 0);
    float4_t accg = __builtin_amdgcn_mfma_f32_16x16x32_f16(afrag[2][4], bm, zero4, 0, 0, 0);
#pragma unroll
    for (int kb = 0; kb < 4; ++kb)
      accg = __builtin_amdgcn_mfma_f32_16x16x32_f16(afrag[2][kb], gf[kb], accg, 0, 0, 0);
    __builtin_amdgcn_s_setprio(0);

    {  // fused blend, ONE rcp: Eu=e^{-pre_u}, Eg=e^{2*pre_g},
      // c' = [c*(Eg+1) + Eu*(Eg-1)] / [(1+Eu)*(1+Eg)]
      H4U v;
      float cn[4];
#pragma unroll
      for (int r = 0; r < 4; ++r) {
        float Eu = exp2_(accu[r]);
        float Eg = exp2_(accg[r]);
        float d0 = Eg + 1.f;
        float den = fmaf(Eu, d0, d0);
        float num = fmaf(cr[r], Eg, cr[r]) + fmaf(Eu, Eg, -Eu);
        cn[r] = num * rcp_(den);
        cr[r] = cn[r];
      }
      v.h2[0] = __builtin_amdgcn_cvt_pkrtz(cn[0], cn[1]);
      v.h2[1] = __builtin_amdgcn_cvt_pkrtz(cn[2], cn[3]);
      *(unsigned long long*)&Cbuf[(kb_w * 64 + lane_w) * 8 + j0] = v.u;
    }
    // barrier-2 shadow: r-gate lead for step t+1 (register-only)
    accr_p = __builtin_amdgcn_mfma_f32_16x16x32_f16(afrag[0][4], bm_n, zero4, 0, 0, 0);
    __syncthreads();  // B2: c_{t+1} visible; Gbuf reads done
    bm = bm_n;
    pcur = pnext;
  }

  // backward cell at t=63, c0=0: h_back = (1-sig(pre_u))*tanh(pre_g)
  {
    const char* bb_base = (const char*)msgb16 +
                          ((size_t)(b * 512 + n0 + l15)) * 32 + (q4 & 1) * 16;
    const char* bp = (q4 < 2) ? bb_base : (const char*)zpad;
    half8_t bbk = *(const half8_t*)bp;
    half8_t au_f = *(const half8_t*)&wbfrag[(size_t)((og * 2 + 0) * 512) + lane * 8];
    half8_t ag_f = *(const half8_t*)&wbfrag[(size_t)((og * 2 + 1) * 512) + lane * 8];
    float4_t au = __builtin_amdgcn_mfma_f32_16x16x32_f16(au_f, bbk, zero4, 0, 0, 0);
    float4_t ag = __builtin_amdgcn_mfma_f32_16x16x32_f16(ag_f, bbk, zero4, 0, 0, 0);
#pragma unroll
    for (int r = 0; r < 4; ++r) {
      int row = og * 16 + q4 * 4 + r;
      float uu2 = rcp_(1.f + exp2_(au[r]));
      float gg = fmaf(-2.f, rcp_(exp2_(ag[r]) + 1.f), 1.f);
      hb_lds[row * 16 + l15] = (1.f - uu2) * gg;
      hf_lds[row * 16 + l15] = cr[r];
    }
  }
  __syncthreads();

  // decoder
  if (tid < 192) {
    int i = tid >> 4, cc = tid & 15;
    const float* dwa = dec_w + (size_t)i * 512;
    const float* dwb = dwa + 256;
    float hd = dec_b[i];
    for (int e = 0; e < 128; ++e) {
      hd = fmaf(dwa[e] + dwb[e], hf_lds[e * 16 + cc], hd);
      hd = fmaf(dwa[128 + e] + dwb[128 + e], hb_lds[e * 16 + cc], hd);
    }
    hdec_lds[i * 16 + cc] = hd;
  }
  __syncthreads();
  if (tid < 192) {
    int o = tid >> 4, cc = tid & 15;
    float v = out_b[o];
#pragma unroll
    for (int i = 0; i < 12; ++i) v = fmaf(out_w[o * 12 + i], hdec_lds[i * 16 + cc], v);
    out[((size_t)(b * 12 + o)) * 512 + n0 + cc] = v;
  }
}

extern "C" void kernel_launch(void* const* d_in, const int* in_sizes, int n_in,
                              void* d_out, int out_size, void* d_ws, size_t ws_size,
                              hipStream_t stream) {
  (void)in_sizes; (void)n_in; (void)out_size; (void)ws_size;
  const float* x     = (const float*)d_in[0];
  const float* adj   = (const float*)d_in[1];
  const float* Wf    = (const float*)d_in[2];
  const float* Uf    = (const float*)d_in[3];
  const float* bf    = (const float*)d_in[4];
  const float* E1f   = (const float*)d_in[5];
  const float* E2f   = (const float*)d_in[6];
  const float* Wb    = (const float*)d_in[7];
  const float* bb    = (const float*)d_in[9];
  const float* E1b   = (const float*)d_in[10];
  const float* E2b   = (const float*)d_in[11];
  const float* dec_w = (const float*)d_in[12];
  const float* dec_b = (const float*)d_in[13];
  const float* out_w = (const float*)d_in[14];
  const float* out_b = (const float*)d_in[15];

  _Float16* h      = (_Float16*)d_ws;
  _Float16* adjT   = h;                        //   262144
  _Float16* AfT    = h + 262144;               //   262144
  _Float16* AbT    = h + 524288;               //   262144
  _Float16* ufrag  = h + 786432;               //    61440
  _Float16* wbfrag = h + 847872;               //     8192
  _Float16* zpad   = h + 856064;               //       64
  _Float16* msg16  = h + 856128;               //  8388608 (32B rows)
  _Float16* msgb16 = h + 9244736;              //   131072 (also t=64 over-read pad)
  // total 9,375,808 halves ≈ 18.75 MB

  prep_kernel<<<1289, 256, 0, stream>>>(E1f, E2f, E1b, E2b, adj, Wf, Uf, bf,
                                        Wb, bb, adjT, AfT, AbT, ufrag, wbfrag, zpad);
  msg_kernel<<<512, 256, 0, stream>>>(x, adjT, AfT, AbT, msg16, msgb16);
  rec_kernel<<<512, 512, 0, stream>>>(msg16, msgb16, zpad, ufrag, wbfrag,
                                      dec_w, dec_b, out_w, out_b, (float*)d_out);
}